// Round 1
// baseline (2730.548 us; speedup 1.0000x reference)
//
#include <hip/hip_runtime.h>

#define NB 4
#define NPTS 8192
#define NPOINT 2048
#define NSAMPLE 32
#define CF 64      // feature channels
#define CIN 67     // 3 + 64
#define G 8        // centers per MLP block

// ---------------- FPS: one block per batch ----------------
__global__ __launch_bounds__(512) void fps_kernel(const float* __restrict__ xyz,
                                                  float* __restrict__ new_xyz) {
  const int b = blockIdx.x;
  const int tid = threadIdx.x;
  __shared__ float sx[NPTS], sy[NPTS], sz[NPTS];
  __shared__ float wval[2][8];
  __shared__ int sfar[2];
  const float* xb = xyz + (size_t)b * NPTS * 3;
  for (int i = tid; i < NPTS; i += 512) {
    sx[i] = xb[3 * i + 0];
    sy[i] = xb[3 * i + 1];
    sz[i] = xb[3 * i + 2];
  }
  if (tid == 0) sfar[0] = 0x7fffffff;
  __syncthreads();
  float px[16], py[16], pz[16], dist[16];
#pragma unroll
  for (int r = 0; r < 16; ++r) {
    int p = tid + (r << 9);
    px[r] = sx[p]; py[r] = sy[p]; pz[r] = sz[p];
    dist[r] = 1e10f;
  }
  int far = 0;
  const int lane = tid & 63;
  for (int it = 0; it < NPOINT; ++it) {
    float cx = sx[far], cy = sy[far], cz = sz[far];
    if (tid == 0) {
      float* o = new_xyz + ((size_t)b * NPOINT + it) * 3;
      o[0] = cx; o[1] = cy; o[2] = cz;
    }
    float tbest = -1.0f;
#pragma unroll
    for (int r = 0; r < 16; ++r) {
      // exact numpy order: (dx*dx + dy*dy) + dz*dz, no FMA contraction
      float dx = px[r] - cx, dy = py[r] - cy, dz = pz[r] - cz;
      float d = __fadd_rn(__fadd_rn(__fmul_rn(dx, dx), __fmul_rn(dy, dy)),
                          __fmul_rn(dz, dz));
      float nd = fminf(dist[r], d);
      dist[r] = nd;
      tbest = fmaxf(tbest, nd);
    }
    float wb = tbest;
#pragma unroll
    for (int m = 1; m < 64; m <<= 1) wb = fmaxf(wb, __shfl_xor(wb, m));
    const int p = it & 1;
    if (lane == 0) wval[p][tid >> 6] = wb;
    __syncthreads();
    if (tid == 0) sfar[p ^ 1] = 0x7fffffff;
    float gmax = wval[p][lane & 7];
#pragma unroll
    for (int m = 1; m < 8; m <<= 1) gmax = fmaxf(gmax, __shfl_xor(gmax, m));
    if (tbest == gmax) {
      int cand = 0x7fffffff;
#pragma unroll
      for (int r = 0; r < 16; ++r)
        if (dist[r] == gmax) cand = min(cand, tid + (r << 9));
      atomicMin(&sfar[p], cand);
    }
    __syncthreads();
    far = sfar[p];
  }
}

// ---------------- feature transpose (B,C,N) -> (B,N,C) ----------------
__global__ __launch_bounds__(256) void tr_kernel(const float* __restrict__ f,
                                                 float* __restrict__ ft) {
  int idx = blockIdx.x * 256 + threadIdx.x;
  int c = idx & 63;
  int i = (idx >> 6) & (NPTS - 1);
  int b = idx >> 19;
  ft[idx] = f[((size_t)(b * CF + c)) * NPTS + i];
}

// ---------------- ball query: one wave per center ----------------
__global__ __launch_bounds__(256) void bq_kernel(const float* __restrict__ xyz,
                                                 const float* __restrict__ new_xyz,
                                                 int* __restrict__ idxbuf) {
  const int lane = threadIdx.x & 63;
  const int gw = (blockIdx.x * 256 + threadIdx.x) >> 6;
  const int b = gw >> 11;
  const int j = gw & 2047;
  const float* xb = xyz + (size_t)b * NPTS * 3;
  const float* c = new_xyz + ((size_t)b * NPOINT + j) * 3;
  const float cx = c[0], cy = c[1], cz = c[2];
  int* out = idxbuf + ((size_t)b * NPOINT + j) * NSAMPLE;
  const float r2 = 0.01f;
  int found = 0, first = 0;
  for (int base = 0; base < NPTS && found < NSAMPLE; base += 64) {
    const int i = base + lane;
    float dx = xb[3 * i + 0] - cx, dy = xb[3 * i + 1] - cy, dz = xb[3 * i + 2] - cz;
    float d = __fadd_rn(__fadd_rn(__fmul_rn(dx, dx), __fmul_rn(dy, dy)),
                        __fmul_rn(dz, dz));
    bool in = (d <= r2);
    unsigned long long mask = __ballot(in);
    if (mask) {
      if (found == 0) first = base + (__ffsll(mask) - 1);
      int slot = found + __popcll(mask & ((1ull << lane) - 1ull));
      if (in && slot < NSAMPLE) out[slot] = i;
      found += (int)__popcll(mask);
    }
  }
  for (int s = found + lane; s < NSAMPLE; s += 64) out[s] = first;
}

// ---------------- fused gather + MLP + max ----------------
__global__ __launch_bounds__(256) void mlp_kernel(const float* __restrict__ xyz,
                                                  const float* __restrict__ ft,
                                                  const float* __restrict__ feat,
                                                  const int* __restrict__ idxbuf,
                                                  const float* __restrict__ new_xyz,
                                                  const float* __restrict__ W0,
                                                  const float* __restrict__ b0,
                                                  const float* __restrict__ W1,
                                                  const float* __restrict__ b1,
                                                  const float* __restrict__ W2,
                                                  const float* __restrict__ b2,
                                                  float* __restrict__ out_nf,
                                                  int use_ft) {
  __shared__ __align__(16) float Ws0[CIN * 64];   // [c][o]
  __shared__ __align__(16) float Ws1[64 * 64];    // [c][o]
  __shared__ __align__(16) float Ws2[64 * 128];   // [c][o]
  __shared__ float bs0[64], bs1[64], bs2[128];
  __shared__ __align__(16) float X0[CIN * 32];    // [c][k]
  __shared__ __align__(16) float X1[64 * 32];     // [c][k]
  const int tid = threadIdx.x;
  const int k = tid & 31;
  const int og = tid >> 5;  // 0..7
  for (int t = tid; t < 64 * CIN; t += 256) {
    int o = t / CIN, c = t - o * CIN;
    Ws0[c * 64 + o] = W0[t];
  }
  for (int t = tid; t < 64 * 64; t += 256) Ws1[(t & 63) * 64 + (t >> 6)] = W1[t];
  for (int t = tid; t < 128 * 64; t += 256) Ws2[(t & 63) * 128 + (t >> 6)] = W2[t];
  if (tid < 64) { bs0[tid] = b0[tid]; bs1[tid] = b1[tid]; }
  if (tid < 128) bs2[tid] = b2[tid];
  __syncthreads();

  for (int g = 0; g < G; ++g) {
    const int cj = blockIdx.x * G + g;
    const int b = cj >> 11;
    const int j = cj & 2047;
    const int ni = idxbuf[cj * NSAMPLE + k];
    if (og == 0) {
      const float* ctr = new_xyz + (size_t)cj * 3;
      const float* pp = xyz + ((size_t)b * NPTS + ni) * 3;
      X0[0 * 32 + k] = pp[0] - ctr[0];
      X0[1 * 32 + k] = pp[1] - ctr[1];
      X0[2 * 32 + k] = pp[2] - ctr[2];
    }
    const int cbase = 3 + og * 8;
    if (use_ft) {
      const float4* fr = (const float4*)(ft + ((size_t)b * NPTS + ni) * CF + og * 8);
      float4 f0 = fr[0], f1 = fr[1];
      X0[(cbase + 0) * 32 + k] = f0.x; X0[(cbase + 1) * 32 + k] = f0.y;
      X0[(cbase + 2) * 32 + k] = f0.z; X0[(cbase + 3) * 32 + k] = f0.w;
      X0[(cbase + 4) * 32 + k] = f1.x; X0[(cbase + 5) * 32 + k] = f1.y;
      X0[(cbase + 6) * 32 + k] = f1.z; X0[(cbase + 7) * 32 + k] = f1.w;
    } else {
      const float* fb = feat + (size_t)b * CF * NPTS + ni;
#pragma unroll
      for (int q = 0; q < 8; ++q)
        X0[(cbase + q) * 32 + k] = fb[(size_t)(og * 8 + q) * NPTS];
    }
    __syncthreads();

    // L0: 67 -> 64
    float acc[8];
#pragma unroll
    for (int i = 0; i < 8; ++i) acc[i] = bs0[og * 8 + i];
    for (int c = 0; c < CIN; ++c) {
      float xv = X0[c * 32 + k];
      const float4* wr = (const float4*)&Ws0[c * 64 + og * 8];
      float4 w0 = wr[0], w1 = wr[1];
      acc[0] = fmaf(w0.x, xv, acc[0]); acc[1] = fmaf(w0.y, xv, acc[1]);
      acc[2] = fmaf(w0.z, xv, acc[2]); acc[3] = fmaf(w0.w, xv, acc[3]);
      acc[4] = fmaf(w1.x, xv, acc[4]); acc[5] = fmaf(w1.y, xv, acc[5]);
      acc[6] = fmaf(w1.z, xv, acc[6]); acc[7] = fmaf(w1.w, xv, acc[7]);
    }
#pragma unroll
    for (int i = 0; i < 8; ++i) X1[(og * 8 + i) * 32 + k] = fmaxf(acc[i], 0.f);
    __syncthreads();

    // L1: 64 -> 64 (reads X1, writes X0)
    float a1[8];
#pragma unroll
    for (int i = 0; i < 8; ++i) a1[i] = bs1[og * 8 + i];
    for (int c = 0; c < 64; ++c) {
      float xv = X1[c * 32 + k];
      const float4* wr = (const float4*)&Ws1[c * 64 + og * 8];
      float4 w0 = wr[0], w1 = wr[1];
      a1[0] = fmaf(w0.x, xv, a1[0]); a1[1] = fmaf(w0.y, xv, a1[1]);
      a1[2] = fmaf(w0.z, xv, a1[2]); a1[3] = fmaf(w0.w, xv, a1[3]);
      a1[4] = fmaf(w1.x, xv, a1[4]); a1[5] = fmaf(w1.y, xv, a1[5]);
      a1[6] = fmaf(w1.z, xv, a1[6]); a1[7] = fmaf(w1.w, xv, a1[7]);
    }
#pragma unroll
    for (int i = 0; i < 8; ++i) X0[(og * 8 + i) * 32 + k] = fmaxf(a1[i], 0.f);
    __syncthreads();

    // L2: 64 -> 128 (reads X0 rows 0..63), fused relu + max over k
    float a2[16];
#pragma unroll
    for (int i = 0; i < 16; ++i) a2[i] = bs2[og * 16 + i];
    for (int c = 0; c < 64; ++c) {
      float xv = X0[c * 32 + k];
      const float4* wr = (const float4*)&Ws2[c * 128 + og * 16];
      float4 w0 = wr[0], w1 = wr[1], w2 = wr[2], w3 = wr[3];
      a2[0]  = fmaf(w0.x, xv, a2[0]);  a2[1]  = fmaf(w0.y, xv, a2[1]);
      a2[2]  = fmaf(w0.z, xv, a2[2]);  a2[3]  = fmaf(w0.w, xv, a2[3]);
      a2[4]  = fmaf(w1.x, xv, a2[4]);  a2[5]  = fmaf(w1.y, xv, a2[5]);
      a2[6]  = fmaf(w1.z, xv, a2[6]);  a2[7]  = fmaf(w1.w, xv, a2[7]);
      a2[8]  = fmaf(w2.x, xv, a2[8]);  a2[9]  = fmaf(w2.y, xv, a2[9]);
      a2[10] = fmaf(w2.z, xv, a2[10]); a2[11] = fmaf(w2.w, xv, a2[11]);
      a2[12] = fmaf(w3.x, xv, a2[12]); a2[13] = fmaf(w3.y, xv, a2[13]);
      a2[14] = fmaf(w3.z, xv, a2[14]); a2[15] = fmaf(w3.w, xv, a2[15]);
    }
#pragma unroll
    for (int i = 0; i < 16; ++i) {
      float v = fmaxf(a2[i], 0.f);
#pragma unroll
      for (int m = 1; m < 32; m <<= 1) v = fmaxf(v, __shfl_xor(v, m));
      a2[i] = v;
    }
    if (k == 0) {
#pragma unroll
      for (int i = 0; i < 16; ++i)
        out_nf[((size_t)b * 128 + og * 16 + i) * NPOINT + j] = a2[i];
    }
    __syncthreads();
  }
}

extern "C" void kernel_launch(void* const* d_in, const int* in_sizes, int n_in,
                              void* d_out, int out_size, void* d_ws, size_t ws_size,
                              hipStream_t stream) {
  (void)in_sizes; (void)n_in; (void)out_size;
  const float* xyz  = (const float*)d_in[0];
  const float* feat = (const float*)d_in[1];
  const float* W0   = (const float*)d_in[2];
  const float* b0   = (const float*)d_in[3];
  const float* W1   = (const float*)d_in[4];
  const float* b1   = (const float*)d_in[5];
  const float* W2   = (const float*)d_in[6];
  const float* b2   = (const float*)d_in[7];
  float* new_xyz = (float*)d_out;
  float* out_nf  = (float*)d_out + (size_t)NB * NPOINT * 3;

  int* idxbuf = (int*)d_ws;
  size_t idx_bytes = (size_t)NB * NPOINT * NSAMPLE * sizeof(int);
  float* ft = (float*)((char*)d_ws + idx_bytes);
  size_t need = idx_bytes + (size_t)NB * NPTS * CF * sizeof(float);
  int use_ft = (ws_size >= need) ? 1 : 0;

  fps_kernel<<<NB, 512, 0, stream>>>(xyz, new_xyz);
  if (use_ft) tr_kernel<<<(NB * NPTS * CF) / 256, 256, 0, stream>>>(feat, ft);
  bq_kernel<<<(NB * NPOINT) / 4, 256, 0, stream>>>(xyz, new_xyz, idxbuf);
  mlp_kernel<<<(NB * NPOINT) / G, 256, 0, stream>>>(xyz, ft, feat, idxbuf, new_xyz,
                                                    W0, b0, W1, b1, W2, b2,
                                                    out_nf, use_ft);
}